// Round 17
// baseline (128.968 us; speedup 1.0000x reference)
//
#include <hip/hip_runtime.h>

typedef unsigned short u16;
typedef float  f32x4   __attribute__((ext_vector_type(4)));
typedef float  f32x16  __attribute__((ext_vector_type(16)));
typedef __bf16 bf16x8  __attribute__((ext_vector_type(8)));
typedef u16    u16x4   __attribute__((ext_vector_type(4)));

#define DEV __device__ __forceinline__

DEV u16 f2bf(float f) {                 // round-to-nearest-even f32 -> bf16 bits
  union { float f; unsigned u; } x; x.f = f;
  unsigned r = x.u + 0x7fffu + ((x.u >> 16) & 1u);
  return (u16)(r >> 16);
}
DEV float bf2f(u16 b) { union { unsigned u; float f; } c; c.u = (unsigned)b << 16; return c.f; }

DEV unsigned cvtpk(float lo, float hi) { // packed bf16 pair: low16=lo, high16=hi (RNE)
  unsigned r;
  asm("v_cvt_pk_bf16_f32 %0, %1, %2" : "=v"(r) : "v"(lo), "v"(hi));
  return r;
}
#if __has_builtin(__builtin_amdgcn_exp2f)
DEV float fexp2(float x) { return __builtin_amdgcn_exp2f(x); }
#else
DEV float fexp2(float x) { return __builtin_exp2f(x); }
#endif

DEV f32x4 mfma16(bf16x8 a, bf16x8 b, f32x4 c) {
  return __builtin_amdgcn_mfma_f32_16x16x32_bf16(a, b, c, 0, 0, 0);
}
DEV f32x16 mfma32(bf16x8 a, bf16x8 b, f32x16 c) {
  return __builtin_amdgcn_mfma_f32_32x32x16_bf16(a, b, c, 0, 0, 0);
}

DEV void gload16(const void* g, void* l) {   // async global->LDS, 16B/lane
  __builtin_amdgcn_global_load_lds(
      (__attribute__((address_space(1))) void*)g,
      (__attribute__((address_space(3))) void*)l, 16, 0, 0);
}

#define WAIT(N) asm volatile("s_waitcnt vmcnt(" #N ")" ::: "memory")
#define BAR()   __builtin_amdgcn_s_barrier()

// ---------------------------------------------------------- LN row body (shared)
template<typename LOADER>
DEV void ln_body(LOADER load, const float* __restrict__ g, const float* __restrict__ bta,
                 u16* __restrict__ yrow, int C, float outscale, float* red)
{
  const int tid = threadIdx.x;
  const int n4 = C >> 2;
  f32x4 v = {0.f, 0.f, 0.f, 0.f};
  if (tid < n4) v = load(tid);
  float s1 = v[0] + v[1] + v[2] + v[3];
  float s2 = v[0]*v[0] + v[1]*v[1] + v[2]*v[2] + v[3]*v[3];
#pragma unroll
  for (int o = 32; o > 0; o >>= 1) {
    s1 += __shfl_xor(s1, o, 64);
    s2 += __shfl_xor(s2, o, 64);
  }
  const int lane = tid & 63, wv = tid >> 6;
  if (lane == 0) { red[wv] = s1; red[4 + wv] = s2; }
  __syncthreads();
  s1 = red[0] + red[1] + red[2] + red[3];
  s2 = red[4] + red[5] + red[6] + red[7];
  const float mu = s1 / C;
  const float rs = rsqrtf(s2 / C - mu * mu + 1e-5f);
  if (tid < n4) {
    f32x4 gg = *(const f32x4*)(g + 4 * tid);
    f32x4 bb = *(const f32x4*)(bta + 4 * tid);
    u16x4 o4;
#pragma unroll
    for (int j = 0; j < 4; ++j)
      o4[j] = f2bf(((v[j] - mu) * rs * gg[j] + bb[j]) * outscale);
    *(u16x4*)(yrow + 4 * tid) = o4;
  }
}

// ---------------------------------------------------------------------- prep
__global__ __launch_bounds__(256)
void prep(const float* __restrict__ Wq, const float* __restrict__ Wk,
          const float* __restrict__ Wv, const float* __restrict__ Wo,
          u16* __restrict__ WqT, u16* __restrict__ WkvT, u16* __restrict__ WoT,
          const float* __restrict__ tabx, const float* __restrict__ tab_g,
          const float* __restrict__ tab_b,
          const float* __restrict__ x, const float* __restrict__ vid_g,
          const float* __restrict__ vid_b,
          u16* __restrict__ kvn, u16* __restrict__ xn)
{
  __shared__ float t[32][33];
  __shared__ float red[8];
  const int bid = blockIdx.x;
  const int tid = threadIdx.x;
  if (bid < 3840) {                  // ---- weight transposes
    const float* src; u16* dst; int K, N, k0, n0;
    if (bid < 3072) {
      const int w = bid / 768, r = bid % 768;
      src = (w == 0) ? Wq : (w == 1) ? Wk : Wv;
      dst = (w == 0) ? WqT : (w == 1) ? WkvT : WkvT + (size_t)768 * 1024;
      K = 1024; N = 768; k0 = (r % 32) * 32; n0 = (r / 32) * 32;
    } else {
      const int r = bid - 3072;
      src = Wo; dst = WoT;
      K = 768; N = 1024; k0 = (r % 24) * 32; n0 = (r / 24) * 32;
    }
    const int tx = tid & 31, ty = tid >> 5;
#pragma unroll
    for (int i = ty; i < 32; i += 8)
      t[i][tx] = src[(size_t)(k0 + i) * N + n0 + tx];
    __syncthreads();
#pragma unroll
    for (int i = ty; i < 32; i += 8)
      dst[(size_t)(n0 + i) * K + k0 + tx] = f2bf(t[tx][i]);
  } else {                           // ---- input LN (C=1024)
    const int r = bid - 3840;
    const float* xr; const float *g, *bb; u16* y;
    if (r < 4096) { xr = tabx + (size_t)r * 1024; g = tab_g; bb = tab_b;
                    y = kvn + (size_t)r * 1024; }
    else { const int rr = r - 4096; xr = x + (size_t)rr * 1024; g = vid_g;
           bb = vid_b; y = xn + (size_t)rr * 1024; }
    ln_body([&](int i) { return *(const f32x4*)(xr + 4 * i); }, g, bb, y, 1024, 1.0f, red);
  }
}

// ------------------------------------------------------------------ gemm_qkv
// (round-12/15 proven sync structure) 128x128 tile, BK=32, 4 waves, acc[4][4];
// 2-buffer counted-vmcnt(4); bijective ((row>>1)&3)<<4 swizzle (0 conflicts).
// NEW: marching global pointers (+64B/step) + hoisted LDS read offsets —
// removes ~48 VALU address ops per step (VALUBusy was 38% = addr arithmetic).
__global__ __launch_bounds__(256)
void gemm_qkv(const u16* __restrict__ xn, const u16* __restrict__ kvn,
              const u16* __restrict__ WqT, const u16* __restrict__ WkvT,
              u16* __restrict__ q_pre, u16* __restrict__ k_pre, u16* __restrict__ vT)
{
  __shared__ __align__(16) u16 As[2][128 * 32];   // 2 x 8 KB
  __shared__ __align__(16) u16 Bs[2][128 * 32];   // 2 x 8 KB
  const int bid = blockIdx.x;
  const int tid  = threadIdx.x;
  const int lane = tid & 63;
  const int wave = tid >> 6;
  const bool isq = bid >= 384;
  const u16* A; const u16* Bt; int bm, bn;
  if (!isq) { A = kvn;  Bt = WkvT; bm = (bid & 31) * 128;  bn = (bid >> 5) * 128; }
  else { const int r = bid - 384; A = xn; Bt = WqT; bm = (r & 63) * 128; bn = (r >> 6) * 128; }
  const int wm = (wave >> 1) * 64;
  const int wn = (wave & 1) * 64;
  const int fr = lane & 15;
  const int fkb = (lane >> 4) * 16;

  f32x4 acc[4][4] = {};

  // ---- marching global pointers (advance +64 B per K-step)
  const char* pA0; const char* pA1; const char* pB0; const char* pB1;
  {
    const char* gA0 = (const char*)(A  + (size_t)bm * 1024);
    const char* gB0 = (const char*)(Bt + (size_t)bn * 1024);
    const int o0 = tid * 16, o1 = tid * 16 + 4096;
    const int r0 = o0 >> 6, r1 = o1 >> 6;
    const int s0 = (o0 & 63) ^ (((r0 >> 1) & 3) << 4);
    const int s1 = (o1 & 63) ^ (((r1 >> 1) & 3) << 4);
    pA0 = gA0 + (size_t)r0 * 2048 + s0;  pA1 = gA0 + (size_t)r1 * 2048 + s1;
    pB0 = gB0 + (size_t)r0 * 2048 + s0;  pB1 = gB0 + (size_t)r1 * 2048 + s1;
  }
  char* const dA0 = (char*)&As[0][0] + wave * 1024;
  char* const dB0 = (char*)&Bs[0][0] + wave * 1024;

  auto stage = [&](int buf) {                // 4 loads, order A0,B0,A1,B1 (fixed)
    char* da = dA0 + (buf << 13);
    char* db = dB0 + (buf << 13);
    gload16(pA0, da);        gload16(pB0, db);
    gload16(pA1, da + 4096); gload16(pB1, db + 4096);
    pA0 += 64; pA1 += 64; pB0 += 64; pB1 += 64;
  };

  // ---- hoisted swizzled LDS read offsets (loop-invariant)
  int offA[4], offB[4];
#pragma unroll
  for (int m = 0; m < 4; ++m) {
    const int row = wm + m * 16 + fr;
    offA[m] = row * 64 + (fkb ^ (((row >> 1) & 3) << 4));
  }
#pragma unroll
  for (int n = 0; n < 4; ++n) {
    const int row = wn + n * 16 + fr;
    offB[n] = row * 64 + (fkb ^ (((row >> 1) & 3) << 4));
  }

  auto step = [&](int cur) {
    const char* ba = (const char*)&As[0][0] + (cur << 13);
    const char* bb = (const char*)&Bs[0][0] + (cur << 13);
    bf16x8 af[4], bg[4];
#pragma unroll
    for (int m = 0; m < 4; ++m) af[m] = *(const bf16x8*)(ba + offA[m]);
#pragma unroll
    for (int n = 0; n < 4; ++n) bg[n] = *(const bf16x8*)(bb + offB[n]);
#pragma unroll
    for (int m = 0; m < 4; ++m)
#pragma unroll
      for (int n = 0; n < 4; ++n)
        acc[m][n] = mfma16(af[m], bg[n], acc[m][n]);
  };

  stage(0);
#pragma unroll 1
  for (int t = 0; t < 31; ++t) {
    stage((t & 1) ^ 1);                      // prefetch: 4 loads stay in flight
    WAIT(4);                                 // wait THIS tile only
    BAR();
    step(t & 1);
    BAR();                                   // reads of cur done before restage
    asm volatile("" ::: "memory");
  }
  WAIT(0);
  BAR();
  step(31 & 1);

  const int orow0 = bm + wm + 4 * (lane >> 4);
  const int ocol0 = bn + wn + fr;
#pragma unroll
  for (int m = 0; m < 4; ++m)
#pragma unroll
    for (int n = 0; n < 4; ++n) {
      const int row0 = orow0 + m * 16;
      const int col  = ocol0 + n * 16;
      if (isq) {
#pragma unroll
        for (int r = 0; r < 4; ++r)
          q_pre[(size_t)(row0 + r) * 768 + col] = f2bf(acc[m][n][r]);
      } else if (col < 768) {
#pragma unroll
        for (int r = 0; r < 4; ++r)
          k_pre[(size_t)(row0 + r) * 768 + col] = f2bf(acc[m][n][r]);
      } else {
        // v output written directly transposed: vT[(b*12+h)*64+d][j]
        const int c2 = col - 768, hh = c2 >> 6, dd = c2 & 63;
        const int bb2 = row0 >> 10, jj = row0 & 1023;
        u16x4 o4;
#pragma unroll
        for (int r = 0; r < 4; ++r) o4[r] = f2bf(acc[m][n][r]);
        *(u16x4*)(vT + ((size_t)(bb2 * 12 + hh) * 64 + dd) * 1024 + jj) = o4;
      }
    }
}

// --------------------------------------------------------------------- ln_qk
__global__ __launch_bounds__(256)
void ln_qk(const u16* __restrict__ k_pre, const float* __restrict__ k_g,
           const float* __restrict__ k_b, u16* __restrict__ kb,
           const u16* __restrict__ q_pre, const float* __restrict__ q_g,
           const float* __restrict__ q_b, u16* __restrict__ qb)
{
  __shared__ float red[8];
  const int bid = blockIdx.x;
  const bool isk = bid < 4096;
  const int row = isk ? bid : bid - 4096;
  const u16* xr = (isk ? k_pre : q_pre) + (size_t)row * 768;
  u16* y = (isk ? kb : qb) + (size_t)row * 768;
  const float sc = isk ? 1.0f : 0.125f * 1.44269504089f;
  ln_body([&](int i) {
    const u16x4 raw = *(const u16x4*)(xr + 4 * i);
    f32x4 v;
#pragma unroll
    for (int j = 0; j < 4; ++j) v[j] = bf2f(raw[j]);
    return v;
  }, isk ? k_g : q_g, isk ? k_b : q_b, y, 768, sc, red);
}

// --------------------------------------------------------------- attention v8d
// (round-12 proven sync structure) No-max exp2 softmax; lane-local denominator;
// 2-buffer K/V counted-vmcnt(4); x2-unrolled loop. NEW: marching global
// pointers for K/V staging (K += 96KB, V += 128B per tile).
__global__ __launch_bounds__(256, 3)
void attn7(const u16* __restrict__ q, const u16* __restrict__ k,
           const u16* __restrict__ vT, u16* __restrict__ att)
{
  __shared__ __align__(16) u16 Ks[2][64 * 64];
  __shared__ __align__(16) u16 Vs[2][64 * 64];
  __shared__ __align__(16) u16 osm[4][32][72];

  const int bh = blockIdx.x;
  const int b = bh / 12, h = bh - b * 12;
  const int tid = threadIdx.x, lane = tid & 63, wave = tid >> 6;
  const int lq  = lane & 31;
  const int hi5 = lane >> 5;
  const int qrow = blockIdx.y * 128 + wave * 32 + lq;

  const u16* qp = q + (size_t)(b * 2048 + qrow) * 768 + h * 64 + hi5 * 8;
  bf16x8 qf[4];
#pragma unroll
  for (int ds = 0; ds < 4; ++ds) qf[ds] = *(const bf16x8*)(qp + ds * 16);

  f32x16 ot0 = {}, ot1 = {};
  float l0 = 0.f, l1 = 0.f, l2 = 0.f, l3 = 0.f;   // lane-local partial denominators

  const int rsw0 = (lq & 7) << 4;

  // ---- marching global pointers for staging
  const char* pk0; const char* pk1; const char* pv0; const char* pv1;
  {
    const char* kg = (const char*)k + (size_t)(b * 1024) * 1536 + h * 128;
    const char* vg = (const char*)vT + (size_t)bh * 64 * 2048;
    const int o0 = tid * 16, o1 = tid * 16 + 4096;
    const int r0 = o0 >> 7, r1 = o1 >> 7;
    const int s0 = (o0 & 127) ^ ((r0 & 7) << 4);
    const int s1 = (o1 & 127) ^ ((r1 & 7) << 4);
    pk0 = kg + (size_t)r0 * 1536 + s0;  pk1 = kg + (size_t)r1 * 1536 + s1;
    pv0 = vg + (size_t)r0 * 2048 + s0;  pv1 = vg + (size_t)r1 * 2048 + s1;
  }
  char* const dK0 = (char*)&Ks[0][0] + wave * 1024;
  char* const dV0 = (char*)&Vs[0][0] + wave * 1024;

  auto stage = [&](int buf) {                // order K0,V0,K1,V1 (fixed; 4 loads)
    char* dk = dK0 + (buf << 13);
    char* dv = dV0 + (buf << 13);
    gload16(pk0, dk);        gload16(pv0, dv);
    gload16(pk1, dk + 4096); gload16(pv1, dv + 4096);
    pk0 += 64 * 1536; pk1 += 64 * 1536;      // next 64 j-rows
    pv0 += 128;       pv1 += 128;            // next 64 j-cols (bf16)
  };

  auto step = [&](int cur) {
    // ---- S^T = K * Q^T
    f32x16 st0 = {}, st1 = {};
    __builtin_amdgcn_s_setprio(1);
#pragma unroll
    for (int ds = 0; ds < 4; ++ds) {
      const int cb = ds * 32 + hi5 * 16;
      const bf16x8 k0 = *(const bf16x8*)((const char*)&Ks[cur][0] + lq * 128 + (cb ^ rsw0));
      const bf16x8 k1 = *(const bf16x8*)((const char*)&Ks[cur][0] + (lq + 32) * 128 + (cb ^ rsw0));
      st0 = mfma32(k0, qf[ds], st0);
      st1 = mfma32(k1, qf[ds], st1);
    }
    __builtin_amdgcn_s_setprio(0);
    // ---- exp2 (no max subtraction), lane-local partial sums
#pragma unroll
    for (int r = 0; r < 16; r += 4) {
      float p0 = fexp2(st0[r]);     st0[r]     = p0; l0 += p0;
      float p1 = fexp2(st0[r + 1]); st0[r + 1] = p1; l1 += p1;
      float p2 = fexp2(st0[r + 2]); st0[r + 2] = p2; l2 += p2;
      float p3 = fexp2(st0[r + 3]); st0[r + 3] = p3; l3 += p3;
    }
#pragma unroll
    for (int r = 0; r < 16; r += 4) {
      float p0 = fexp2(st1[r]);     st1[r]     = p0; l0 += p0;
      float p1 = fexp2(st1[r + 1]); st1[r + 1] = p1; l1 += p1;
      float p2 = fexp2(st1[r + 2]); st1[r + 2] = p2; l2 += p2;
      float p3 = fexp2(st1[r + 3]); st1[r + 3] = p3; l3 += p3;
    }
    // ---- PV
    __builtin_amdgcn_s_setprio(1);
#pragma unroll
    for (int s4 = 0; s4 < 4; ++s4) {
      const int u = (s4 & 1) * 8;
      float a0, a1, a2, a3, b0, b1, b2, b3;
      if (s4 < 2) {
        a0 = st0[u]; a1 = st0[u + 1]; a2 = st0[u + 2]; a3 = st0[u + 3];
        b0 = st0[u + 4]; b1 = st0[u + 5]; b2 = st0[u + 6]; b3 = st0[u + 7];
      } else {
        a0 = st1[u]; a1 = st1[u + 1]; a2 = st1[u + 2]; a3 = st1[u + 3];
        b0 = st1[u + 4]; b1 = st1[u + 5]; b2 = st1[u + 6]; b3 = st1[u + 7];
      }
      const unsigned L0 = cvtpk(a0, a1), L1 = cvtpk(a2, a3);
      const unsigned H0 = cvtpk(b0, b1), H1 = cvtpk(b2, b3);
      const auto w02 = __builtin_amdgcn_permlane32_swap(L0, H0, false, false);
      const auto w13 = __builtin_amdgcn_permlane32_swap(L1, H1, false, false);
      union BU { unsigned w[4]; bf16x8 v; } pu;
      pu.w[0] = w02[0]; pu.w[1] = w13[0]; pu.w[2] = w02[1]; pu.w[3] = w13[1];
      const int cb = s4 * 32 + hi5 * 16;
      const bf16x8 v0 = *(const bf16x8*)((const char*)&Vs[cur][0] + lq * 128 + (cb ^ rsw0));
      const bf16x8 v1 = *(const bf16x8*)((const char*)&Vs[cur][0] + (lq + 32) * 128 + (cb ^ rsw0));
      ot0 = mfma32(v0, pu.v, ot0);
      ot1 = mfma32(v1, pu.v, ot1);
    }
    __builtin_amdgcn_s_setprio(0);
  };

  // tiles 0..15; tile n lives in buf n&1; loop unrolled x2 for compile-time cur
  stage(0);
#pragma unroll 1
  for (int tt = 0; tt < 7; ++tt) {
    stage(1);
    WAIT(4);
    BAR();
    step(0);
    BAR();
    stage(0);
    WAIT(4);
    BAR();
    step(1);
    BAR();
    asm volatile("" ::: "memory");
  }
  stage(1);
  WAIT(4);
  BAR();
  step(0);                                   // tile 14
  BAR();
  WAIT(0);
  BAR();
  step(1);                                   // tile 15

  // ---- final denominator: lane-local partials + one cross-half reduce
  float l = (l0 + l1) + (l2 + l3);
  l += __shfl_xor(l, 32, 64);
  const float inv = 1.0f / l;
  // ---- epilogue: normalize, transpose via LDS (osm region), coalesced store
#pragma unroll
  for (int r = 0; r < 16; ++r) {
    const int d0 = (r & 3) + 8 * (r >> 2) + 4 * hi5;
    osm[wave][lq][d0]      = f2bf(ot0[r] * inv);
    osm[wave][lq][32 + d0] = f2bf(ot1[r] * inv);
  }
  asm volatile("s_waitcnt lgkmcnt(0)" ::: "memory");   // intra-wave DS RAW fence
  const int col = (lane & 7) * 8;
#pragma unroll
  for (int pass = 0; pass < 4; ++pass) {
    const int row = pass * 8 + (lane >> 3);
    const bf16x8 vv = *(const bf16x8*)&osm[wave][row][col];
    const int qg = blockIdx.y * 128 + wave * 32 + row;
    *(bf16x8*)(att + (size_t)(b * 2048 + qg) * 768 + h * 64 + col) = vv;
  }
}

// ------------------------------------------------------------------- gemm_o
// d_out[8192][1024] = attb[8192][768] x WoT[1024][768]^T + bo.
// Same structure + marching pointers; K=768 -> 24 steps.
__global__ __launch_bounds__(256)
void gemm_o(const u16* __restrict__ A, const u16* __restrict__ Bt,
            float* __restrict__ Cp, const float* __restrict__ bias)
{
  __shared__ __align__(16) u16 As[2][128 * 32];
  __shared__ __align__(16) u16 Bs[2][128 * 32];
  const int tid  = threadIdx.x;
  const int lane = tid & 63;
  const int wave = tid >> 6;
  const int bm = blockIdx.x * 128;
  const int bn = blockIdx.y * 128;
  const int wm = (wave >> 1) * 64;
  const int wn = (wave & 1) * 64;
  const int fr = lane & 15;
  const int fkb = (lane >> 4) * 16;

  f32x4 acc[4][4] = {};

  const char* pA0; const char* pA1; const char* pB0; const char* pB1;
  {
    const char* gA0 = (const char*)(A  + (size_t)bm * 768);
    const char* gB0 = (const char*)(Bt + (size_t)bn * 768);
    const int o0 = tid * 16, o1 = tid * 16 + 4096;
    const int r0 = o0 >> 6, r1 = o1 >> 6;
    const int s0 = (o0 & 63) ^ (((r0 >> 1) & 3) << 4);
    const int s1 = (o1 & 63) ^ (((r1 >> 1) & 3) << 4);
    pA0 = gA0 + (size_t)r0 * 1536 + s0;  pA1 = gA0 + (size_t)r1 * 1536 + s1;
    pB0 = gB0 + (size_t)r0 * 1536 + s0;  pB1 = gB0 + (size_t)r1 * 1536 + s1;
  }
  char* const dA0 = (char*)&As[0][0] + wave * 1024;
  char* const dB0 = (char*)&Bs[0][0] + wave * 1024;

  auto stage = [&](int buf) {
    char* da = dA0 + (buf << 13);
    char* db = dB0 + (buf << 13);
    gload16(pA0, da);        gload16(pB0, db);
    gload16(pA1, da + 4096); gload16(pB1, db + 4096);
    pA0 += 64; pA1 += 64; pB0 += 64; pB1 += 64;
  };

  int offA[4], offB[4];
#pragma unroll
  for (int m = 0; m < 4; ++m) {
    const int row = wm + m * 16 + fr;
    offA[m] = row * 64 + (fkb ^ (((row >> 1) & 3) << 4));
  }
#pragma unroll
  for (int n = 0; n < 4; ++n) {
    const int row = wn + n * 16 + fr;
    offB[n] = row * 64 + (fkb ^ (((row >> 1) & 3) << 4));
  }

  auto step = [&](int cur) {
    const char* ba = (const char*)&As[0][0] + (cur << 13);
    const char* bb = (const char*)&Bs[0][0] + (cur << 13);
    bf16x8 af[4], bg[4];
#pragma unroll
    for (int m = 0; m < 4; ++m) af[m] = *(const bf16x8*)(ba + offA[m]);
#pragma unroll
    for (int n = 0; n < 4; ++n) bg[n] = *(const bf16x8*)(bb + offB[n]);
#pragma unroll
    for (int m = 0; m < 4; ++m)
#pragma unroll
      for (int n = 0; n < 4; ++n)
        acc[m][n] = mfma16(af[m], bg[n], acc[m][n]);
  };

  stage(0);
#pragma unroll 1
  for (int t = 0; t < 23; ++t) {
    stage((t & 1) ^ 1);
    WAIT(4);
    BAR();
    step(t & 1);
    BAR();
    asm volatile("" ::: "memory");
  }
  WAIT(0);
  BAR();
  step(23 & 1);

  const int orow0 = bm + wm + 4 * (lane >> 4);
  const int ocol0 = bn + wn + fr;
#pragma unroll
  for (int m = 0; m < 4; ++m)
#pragma unroll
    for (int n = 0; n < 4; ++n)
#pragma unroll
      for (int r = 0; r < 4; ++r) {
        const int row = orow0 + m * 16 + r;
        const int col = ocol0 + n * 16;
        Cp[(size_t)row * 1024 + col] = acc[m][n][r] + bias[col];
      }
}

// ------------------------------------------------------------------ launch
extern "C" void kernel_launch(void* const* d_in, const int* in_sizes, int n_in,
                              void* d_out, int out_size, void* d_ws, size_t ws_size,
                              hipStream_t stream)
{
  const float* x     = (const float*)d_in[0];
  const float* tabx  = (const float*)d_in[1];
  const float* tab_g = (const float*)d_in[2];
  const float* tab_b = (const float*)d_in[3];
  const float* vid_g = (const float*)d_in[4];
  const float* vid_b = (const float*)d_in[5];
  const float* Wq    = (const float*)d_in[6];
  const float* Wk    = (const float*)d_in[7];
  const float* Wv    = (const float*)d_in[8];
  const float* q_g   = (const float*)d_in[9];
  const float* q_b   = (const float*)d_in[10];
  const float* k_g   = (const float*)d_in[11];
  const float* k_b   = (const float*)d_in[12];
  const float* Wo    = (const float*)d_in[13];
  const float* bo    = (const float*)d_in[14];

  char* ws = (char*)d_ws;
  const size_t O_WQT  = 0;
  const size_t O_WKVT = O_WQT  + (size_t)768 * 1024 * 2;   // 1536x1024 (Wk | Wv)
  const size_t O_WOT  = O_WKVT + (size_t)1536 * 1024 * 2;
  const size_t O_XN   = O_WOT  + (size_t)1024 * 768 * 2;
  const size_t O_KVN  = O_XN   + (size_t)8192 * 1024 * 2;
  const size_t O_QPRE = O_KVN  + (size_t)4096 * 1024 * 2;
  const size_t O_KPRE = O_QPRE + (size_t)8192 * 768 * 2;
  const size_t O_QB   = O_KPRE + (size_t)4096 * 768 * 2;
  const size_t O_KB   = O_QB   + (size_t)8192 * 768 * 2;
  const size_t O_VT   = O_KB   + (size_t)4096 * 768 * 2;
  const size_t O_ATT  = O_QPRE;   // alias: q_pre dead after its LN

  u16*   WqT   = (u16*)(ws + O_WQT);
  u16*   WkvT  = (u16*)(ws + O_WKVT);
  u16*   WoT   = (u16*)(ws + O_WOT);
  u16*   xn    = (u16*)(ws + O_XN);
  u16*   kvn   = (u16*)(ws + O_KVN);
  u16*   q_pre = (u16*)(ws + O_QPRE);
  u16*   k_pre = (u16*)(ws + O_KPRE);
  u16*   qb    = (u16*)(ws + O_QB);
  u16*   kb    = (u16*)(ws + O_KB);
  u16*   vT    = (u16*)(ws + O_VT);
  u16*   attb  = (u16*)(ws + O_ATT);

  prep<<<16128, 256, 0, stream>>>(Wq, Wk, Wv, Wo, WqT, WkvT, WoT,
                                  tabx, tab_g, tab_b, x, vid_g, vid_b, kvn, xn);
  gemm_qkv<<<768, 256, 0, stream>>>(xn, kvn, WqT, WkvT, q_pre, k_pre, vT);
  ln_qk<<<12288, 256, 0, stream>>>(k_pre, k_g, k_b, kb, q_pre, q_g, q_b, qb);
  attn7<<<dim3(48, 16), 256, 0, stream>>>(qb, kb, vT, attb);
  gemm_o<<<dim3(64, 8), 256, 0, stream>>>(attb, WoT, (float*)d_out, bo);
}

// Round 18
// 127.906 us; speedup vs baseline: 1.0083x; 1.0083x over previous
//
#include <hip/hip_runtime.h>

typedef unsigned short u16;
typedef float  f32x4   __attribute__((ext_vector_type(4)));
typedef float  f32x16  __attribute__((ext_vector_type(16)));
typedef __bf16 bf16x8  __attribute__((ext_vector_type(8)));
typedef u16    u16x4   __attribute__((ext_vector_type(4)));

#define DEV __device__ __forceinline__

DEV u16 f2bf(float f) {                 // round-to-nearest-even f32 -> bf16 bits
  union { float f; unsigned u; } x; x.f = f;
  unsigned r = x.u + 0x7fffu + ((x.u >> 16) & 1u);
  return (u16)(r >> 16);
}
DEV float bf2f(u16 b) { union { unsigned u; float f; } c; c.u = (unsigned)b << 16; return c.f; }

DEV unsigned cvtpk(float lo, float hi) { // packed bf16 pair: low16=lo, high16=hi (RNE)
  unsigned r;
  asm("v_cvt_pk_bf16_f32 %0, %1, %2" : "=v"(r) : "v"(lo), "v"(hi));
  return r;
}
#if __has_builtin(__builtin_amdgcn_exp2f)
DEV float fexp2(float x) { return __builtin_amdgcn_exp2f(x); }
#else
DEV float fexp2(float x) { return __builtin_exp2f(x); }
#endif

DEV f32x4 mfma16(bf16x8 a, bf16x8 b, f32x4 c) {
  return __builtin_amdgcn_mfma_f32_16x16x32_bf16(a, b, c, 0, 0, 0);
}
DEV f32x16 mfma32(bf16x8 a, bf16x8 b, f32x16 c) {
  return __builtin_amdgcn_mfma_f32_32x32x16_bf16(a, b, c, 0, 0, 0);
}

DEV void gload16(const void* g, void* l) {   // async global->LDS, 16B/lane
  __builtin_amdgcn_global_load_lds(
      (__attribute__((address_space(1))) void*)g,
      (__attribute__((address_space(3))) void*)l, 16, 0, 0);
}

#define WAIT(N) asm volatile("s_waitcnt vmcnt(" #N ")" ::: "memory")
#define BAR()   __builtin_amdgcn_s_barrier()

// ---------------------------------------------------------- LN row body (shared)
template<typename LOADER>
DEV void ln_body(LOADER load, const float* __restrict__ g, const float* __restrict__ bta,
                 u16* __restrict__ yrow, int C, float outscale, float* red)
{
  const int tid = threadIdx.x;
  const int n4 = C >> 2;
  f32x4 v = {0.f, 0.f, 0.f, 0.f};
  if (tid < n4) v = load(tid);
  float s1 = v[0] + v[1] + v[2] + v[3];
  float s2 = v[0]*v[0] + v[1]*v[1] + v[2]*v[2] + v[3]*v[3];
#pragma unroll
  for (int o = 32; o > 0; o >>= 1) {
    s1 += __shfl_xor(s1, o, 64);
    s2 += __shfl_xor(s2, o, 64);
  }
  const int lane = tid & 63, wv = tid >> 6;
  if (lane == 0) { red[wv] = s1; red[4 + wv] = s2; }
  __syncthreads();
  s1 = red[0] + red[1] + red[2] + red[3];
  s2 = red[4] + red[5] + red[6] + red[7];
  const float mu = s1 / C;
  const float rs = rsqrtf(s2 / C - mu * mu + 1e-5f);
  if (tid < n4) {
    f32x4 gg = *(const f32x4*)(g + 4 * tid);
    f32x4 bb = *(const f32x4*)(bta + 4 * tid);
    u16x4 o4;
#pragma unroll
    for (int j = 0; j < 4; ++j)
      o4[j] = f2bf(((v[j] - mu) * rs * gg[j] + bb[j]) * outscale);
    *(u16x4*)(yrow + 4 * tid) = o4;
  }
}

// ---------------------------------------------------------------------- prep
// NEW: LN block->row mapping permuted so each 128-row A-panel is written by
// blocks on ONE XCD (writer XCD i%8 == reader XCD (row/128)%8 under the bid%8
// dispatch heuristic). row = 128*(i&7) + ((i>>3)&127) + ((i>>10)<<10) is a
// bijection with (row/128)%8 == i%8. Pure permutation: zero correctness risk.
__global__ __launch_bounds__(256)
void prep(const float* __restrict__ Wq, const float* __restrict__ Wk,
          const float* __restrict__ Wv, const float* __restrict__ Wo,
          u16* __restrict__ WqT, u16* __restrict__ WkvT, u16* __restrict__ WoT,
          const float* __restrict__ tabx, const float* __restrict__ tab_g,
          const float* __restrict__ tab_b,
          const float* __restrict__ x, const float* __restrict__ vid_g,
          const float* __restrict__ vid_b,
          u16* __restrict__ kvn, u16* __restrict__ xn)
{
  __shared__ float t[32][33];
  __shared__ float red[8];
  const int bid = blockIdx.x;
  const int tid = threadIdx.x;
  if (bid < 3840) {                  // ---- weight transposes
    const float* src; u16* dst; int K, N, k0, n0;
    if (bid < 3072) {
      const int w = bid / 768, r = bid % 768;
      src = (w == 0) ? Wq : (w == 1) ? Wk : Wv;
      dst = (w == 0) ? WqT : (w == 1) ? WkvT : WkvT + (size_t)768 * 1024;
      K = 1024; N = 768; k0 = (r % 32) * 32; n0 = (r / 32) * 32;
    } else {
      const int r = bid - 3072;
      src = Wo; dst = WoT;
      K = 768; N = 1024; k0 = (r % 24) * 32; n0 = (r / 24) * 32;
    }
    const int tx = tid & 31, ty = tid >> 5;
#pragma unroll
    for (int i = ty; i < 32; i += 8)
      t[i][tx] = src[(size_t)(k0 + i) * N + n0 + tx];
    __syncthreads();
#pragma unroll
    for (int i = ty; i < 32; i += 8)
      dst[(size_t)(n0 + i) * K + k0 + tx] = f2bf(t[tx][i]);
  } else {                           // ---- input LN (C=1024), XCD-colocated rows
    const int r = bid - 3840;
    const float* xr; const float *g, *bb; u16* y;
    if (r < 4096) {
      const int i = r;               // kvn: 4096 rows
      const int row = 128 * (i & 7) + ((i >> 3) & 127) + ((i >> 10) << 10);
      xr = tabx + (size_t)row * 1024; g = tab_g; bb = tab_b;
      y = kvn + (size_t)row * 1024;
    } else {
      const int i = r - 4096;        // xn: 8192 rows
      const int row = 128 * (i & 7) + ((i >> 3) & 127) + ((i >> 10) << 10);
      xr = x + (size_t)row * 1024; g = vid_g; bb = vid_b;
      y = xn + (size_t)row * 1024;
    }
    ln_body([&](int i2) { return *(const f32x4*)(xr + 4 * i2); }, g, bb, y, 1024, 1.0f, red);
  }
}

// ------------------------------------------------------------------ gemm_qkv
// (round-15/16 proven structure) 128x128 tile, BK=32, 4 waves, acc[4][4];
// 2-buffer counted-vmcnt(4); bijective ((row>>1)&3)<<4 swizzle (0 conflicts);
// marching global pointers + hoisted LDS read offsets.
__global__ __launch_bounds__(256)
void gemm_qkv(const u16* __restrict__ xn, const u16* __restrict__ kvn,
              const u16* __restrict__ WqT, const u16* __restrict__ WkvT,
              u16* __restrict__ q_pre, u16* __restrict__ k_pre, u16* __restrict__ vT)
{
  __shared__ __align__(16) u16 As[2][128 * 32];   // 2 x 8 KB
  __shared__ __align__(16) u16 Bs[2][128 * 32];   // 2 x 8 KB
  const int bid = blockIdx.x;
  const int tid  = threadIdx.x;
  const int lane = tid & 63;
  const int wave = tid >> 6;
  const bool isq = bid >= 384;
  const u16* A; const u16* Bt; int bm, bn;
  if (!isq) { A = kvn;  Bt = WkvT; bm = (bid & 31) * 128;  bn = (bid >> 5) * 128; }
  else { const int r = bid - 384; A = xn; Bt = WqT; bm = (r & 63) * 128; bn = (r >> 6) * 128; }
  const int wm = (wave >> 1) * 64;
  const int wn = (wave & 1) * 64;
  const int fr = lane & 15;
  const int fkb = (lane >> 4) * 16;

  f32x4 acc[4][4] = {};

  const char* pA0; const char* pA1; const char* pB0; const char* pB1;
  {
    const char* gA0 = (const char*)(A  + (size_t)bm * 1024);
    const char* gB0 = (const char*)(Bt + (size_t)bn * 1024);
    const int o0 = tid * 16, o1 = tid * 16 + 4096;
    const int r0 = o0 >> 6, r1 = o1 >> 6;
    const int s0 = (o0 & 63) ^ (((r0 >> 1) & 3) << 4);
    const int s1 = (o1 & 63) ^ (((r1 >> 1) & 3) << 4);
    pA0 = gA0 + (size_t)r0 * 2048 + s0;  pA1 = gA0 + (size_t)r1 * 2048 + s1;
    pB0 = gB0 + (size_t)r0 * 2048 + s0;  pB1 = gB0 + (size_t)r1 * 2048 + s1;
  }
  char* const dA0 = (char*)&As[0][0] + wave * 1024;
  char* const dB0 = (char*)&Bs[0][0] + wave * 1024;

  auto stage = [&](int buf) {                // 4 loads, order A0,B0,A1,B1 (fixed)
    char* da = dA0 + (buf << 13);
    char* db = dB0 + (buf << 13);
    gload16(pA0, da);        gload16(pB0, db);
    gload16(pA1, da + 4096); gload16(pB1, db + 4096);
    pA0 += 64; pA1 += 64; pB0 += 64; pB1 += 64;
  };

  int offA[4], offB[4];
#pragma unroll
  for (int m = 0; m < 4; ++m) {
    const int row = wm + m * 16 + fr;
    offA[m] = row * 64 + (fkb ^ (((row >> 1) & 3) << 4));
  }
#pragma unroll
  for (int n = 0; n < 4; ++n) {
    const int row = wn + n * 16 + fr;
    offB[n] = row * 64 + (fkb ^ (((row >> 1) & 3) << 4));
  }

  auto step = [&](int cur) {
    const char* ba = (const char*)&As[0][0] + (cur << 13);
    const char* bb = (const char*)&Bs[0][0] + (cur << 13);
    bf16x8 af[4], bg[4];
#pragma unroll
    for (int m = 0; m < 4; ++m) af[m] = *(const bf16x8*)(ba + offA[m]);
#pragma unroll
    for (int n = 0; n < 4; ++n) bg[n] = *(const bf16x8*)(bb + offB[n]);
#pragma unroll
    for (int m = 0; m < 4; ++m)
#pragma unroll
      for (int n = 0; n < 4; ++n)
        acc[m][n] = mfma16(af[m], bg[n], acc[m][n]);
  };

  stage(0);
#pragma unroll 1
  for (int t = 0; t < 31; ++t) {
    stage((t & 1) ^ 1);                      // prefetch: 4 loads stay in flight
    WAIT(4);                                 // wait THIS tile only
    BAR();
    step(t & 1);
    BAR();                                   // reads of cur done before restage
    asm volatile("" ::: "memory");
  }
  WAIT(0);
  BAR();
  step(31 & 1);

  const int orow0 = bm + wm + 4 * (lane >> 4);
  const int ocol0 = bn + wn + fr;
#pragma unroll
  for (int m = 0; m < 4; ++m)
#pragma unroll
    for (int n = 0; n < 4; ++n) {
      const int row0 = orow0 + m * 16;
      const int col  = ocol0 + n * 16;
      if (isq) {
#pragma unroll
        for (int r = 0; r < 4; ++r)
          q_pre[(size_t)(row0 + r) * 768 + col] = f2bf(acc[m][n][r]);
      } else if (col < 768) {
#pragma unroll
        for (int r = 0; r < 4; ++r)
          k_pre[(size_t)(row0 + r) * 768 + col] = f2bf(acc[m][n][r]);
      } else {
        // v output written directly transposed: vT[(b*12+h)*64+d][j]
        const int c2 = col - 768, hh = c2 >> 6, dd = c2 & 63;
        const int bb2 = row0 >> 10, jj = row0 & 1023;
        u16x4 o4;
#pragma unroll
        for (int r = 0; r < 4; ++r) o4[r] = f2bf(acc[m][n][r]);
        *(u16x4*)(vT + ((size_t)(bb2 * 12 + hh) * 64 + dd) * 1024 + jj) = o4;
      }
    }
}

// --------------------------------------------------------------------- ln_qk
__global__ __launch_bounds__(256)
void ln_qk(const u16* __restrict__ k_pre, const float* __restrict__ k_g,
           const float* __restrict__ k_b, u16* __restrict__ kb,
           const u16* __restrict__ q_pre, const float* __restrict__ q_g,
           const float* __restrict__ q_b, u16* __restrict__ qb)
{
  __shared__ float red[8];
  const int bid = blockIdx.x;
  const bool isk = bid < 4096;
  const int row = isk ? bid : bid - 4096;
  const u16* xr = (isk ? k_pre : q_pre) + (size_t)row * 768;
  u16* y = (isk ? kb : qb) + (size_t)row * 768;
  const float sc = isk ? 1.0f : 0.125f * 1.44269504089f;
  ln_body([&](int i) {
    const u16x4 raw = *(const u16x4*)(xr + 4 * i);
    f32x4 v;
#pragma unroll
    for (int j = 0; j < 4; ++j) v[j] = bf2f(raw[j]);
    return v;
  }, isk ? k_g : q_g, isk ? k_b : q_b, y, 768, sc, red);
}

// --------------------------------------------------------------- attention v8d
// (round-16 passing version) No-max exp2 softmax; lane-local denominator;
// 2-buffer K/V counted-vmcnt(4); x2-unrolled loop; marching global pointers.
__global__ __launch_bounds__(256, 3)
void attn7(const u16* __restrict__ q, const u16* __restrict__ k,
           const u16* __restrict__ vT, u16* __restrict__ att)
{
  __shared__ __align__(16) u16 Ks[2][64 * 64];
  __shared__ __align__(16) u16 Vs[2][64 * 64];
  __shared__ __align__(16) u16 osm[4][32][72];

  const int bh = blockIdx.x;
  const int b = bh / 12, h = bh - b * 12;
  const int tid = threadIdx.x, lane = tid & 63, wave = tid >> 6;
  const int lq  = lane & 31;
  const int hi5 = lane >> 5;
  const int qrow = blockIdx.y * 128 + wave * 32 + lq;

  const u16* qp = q + (size_t)(b * 2048 + qrow) * 768 + h * 64 + hi5 * 8;
  bf16x8 qf[4];
#pragma unroll
  for (int ds = 0; ds < 4; ++ds) qf[ds] = *(const bf16x8*)(qp + ds * 16);

  f32x16 ot0 = {}, ot1 = {};
  float l0 = 0.f, l1 = 0.f, l2 = 0.f, l3 = 0.f;   // lane-local partial denominators

  const int rsw0 = (lq & 7) << 4;

  const char* pk0; const char* pk1; const char* pv0; const char* pv1;
  {
    const char* kg = (const char*)k + (size_t)(b * 1024) * 1536 + h * 128;
    const char* vg = (const char*)vT + (size_t)bh * 64 * 2048;
    const int o0 = tid * 16, o1 = tid * 16 + 4096;
    const int r0 = o0 >> 7, r1 = o1 >> 7;
    const int s0 = (o0 & 127) ^ ((r0 & 7) << 4);
    const int s1 = (o1 & 127) ^ ((r1 & 7) << 4);
    pk0 = kg + (size_t)r0 * 1536 + s0;  pk1 = kg + (size_t)r1 * 1536 + s1;
    pv0 = vg + (size_t)r0 * 2048 + s0;  pv1 = vg + (size_t)r1 * 2048 + s1;
  }
  char* const dK0 = (char*)&Ks[0][0] + wave * 1024;
  char* const dV0 = (char*)&Vs[0][0] + wave * 1024;

  auto stage = [&](int buf) {                // order K0,V0,K1,V1 (fixed; 4 loads)
    char* dk = dK0 + (buf << 13);
    char* dv = dV0 + (buf << 13);
    gload16(pk0, dk);        gload16(pv0, dv);
    gload16(pk1, dk + 4096); gload16(pv1, dv + 4096);
    pk0 += 64 * 1536; pk1 += 64 * 1536;      // next 64 j-rows
    pv0 += 128;       pv1 += 128;            // next 64 j-cols (bf16)
  };

  auto step = [&](int cur) {
    // ---- S^T = K * Q^T
    f32x16 st0 = {}, st1 = {};
    __builtin_amdgcn_s_setprio(1);
#pragma unroll
    for (int ds = 0; ds < 4; ++ds) {
      const int cb = ds * 32 + hi5 * 16;
      const bf16x8 k0 = *(const bf16x8*)((const char*)&Ks[cur][0] + lq * 128 + (cb ^ rsw0));
      const bf16x8 k1 = *(const bf16x8*)((const char*)&Ks[cur][0] + (lq + 32) * 128 + (cb ^ rsw0));
      st0 = mfma32(k0, qf[ds], st0);
      st1 = mfma32(k1, qf[ds], st1);
    }
    __builtin_amdgcn_s_setprio(0);
    // ---- exp2 (no max subtraction), lane-local partial sums
#pragma unroll
    for (int r = 0; r < 16; r += 4) {
      float p0 = fexp2(st0[r]);     st0[r]     = p0; l0 += p0;
      float p1 = fexp2(st0[r + 1]); st0[r + 1] = p1; l1 += p1;
      float p2 = fexp2(st0[r + 2]); st0[r + 2] = p2; l2 += p2;
      float p3 = fexp2(st0[r + 3]); st0[r + 3] = p3; l3 += p3;
    }
#pragma unroll
    for (int r = 0; r < 16; r += 4) {
      float p0 = fexp2(st1[r]);     st1[r]     = p0; l0 += p0;
      float p1 = fexp2(st1[r + 1]); st1[r + 1] = p1; l1 += p1;
      float p2 = fexp2(st1[r + 2]); st1[r + 2] = p2; l2 += p2;
      float p3 = fexp2(st1[r + 3]); st1[r + 3] = p3; l3 += p3;
    }
    // ---- PV
    __builtin_amdgcn_s_setprio(1);
#pragma unroll
    for (int s4 = 0; s4 < 4; ++s4) {
      const int u = (s4 & 1) * 8;
      float a0, a1, a2, a3, b0, b1, b2, b3;
      if (s4 < 2) {
        a0 = st0[u]; a1 = st0[u + 1]; a2 = st0[u + 2]; a3 = st0[u + 3];
        b0 = st0[u + 4]; b1 = st0[u + 5]; b2 = st0[u + 6]; b3 = st0[u + 7];
      } else {
        a0 = st1[u]; a1 = st1[u + 1]; a2 = st1[u + 2]; a3 = st1[u + 3];
        b0 = st1[u + 4]; b1 = st1[u + 5]; b2 = st1[u + 6]; b3 = st1[u + 7];
      }
      const unsigned L0 = cvtpk(a0, a1), L1 = cvtpk(a2, a3);
      const unsigned H0 = cvtpk(b0, b1), H1 = cvtpk(b2, b3);
      const auto w02 = __builtin_amdgcn_permlane32_swap(L0, H0, false, false);
      const auto w13 = __builtin_amdgcn_permlane32_swap(L1, H1, false, false);
      union BU { unsigned w[4]; bf16x8 v; } pu;
      pu.w[0] = w02[0]; pu.w[1] = w13[0]; pu.w[2] = w02[1]; pu.w[3] = w13[1];
      const int cb = s4 * 32 + hi5 * 16;
      const bf16x8 v0 = *(const bf16x8*)((const char*)&Vs[cur][0] + lq * 128 + (cb ^ rsw0));
      const bf16x8 v1 = *(const bf16x8*)((const char*)&Vs[cur][0] + (lq + 32) * 128 + (cb ^ rsw0));
      ot0 = mfma32(v0, pu.v, ot0);
      ot1 = mfma32(v1, pu.v, ot1);
    }
    __builtin_amdgcn_s_setprio(0);
  };

  // tiles 0..15; tile n lives in buf n&1; loop unrolled x2 for compile-time cur
  stage(0);
#pragma unroll 1
  for (int tt = 0; tt < 7; ++tt) {
    stage(1);
    WAIT(4);
    BAR();
    step(0);
    BAR();
    stage(0);
    WAIT(4);
    BAR();
    step(1);
    BAR();
    asm volatile("" ::: "memory");
  }
  stage(1);
  WAIT(4);
  BAR();
  step(0);                                   // tile 14
  BAR();
  WAIT(0);
  BAR();
  step(1);                                   // tile 15

  // ---- final denominator: lane-local partials + one cross-half reduce
  float l = (l0 + l1) + (l2 + l3);
  l += __shfl_xor(l, 32, 64);
  const float inv = 1.0f / l;
  // ---- epilogue: normalize, transpose via LDS (osm region), coalesced store
#pragma unroll
  for (int r = 0; r < 16; ++r) {
    const int d0 = (r & 3) + 8 * (r >> 2) + 4 * hi5;
    osm[wave][lq][d0]      = f2bf(ot0[r] * inv);
    osm[wave][lq][32 + d0] = f2bf(ot1[r] * inv);
  }
  asm volatile("s_waitcnt lgkmcnt(0)" ::: "memory");   // intra-wave DS RAW fence
  const int col = (lane & 7) * 8;
#pragma unroll
  for (int pass = 0; pass < 4; ++pass) {
    const int row = pass * 8 + (lane >> 3);
    const bf16x8 vv = *(const bf16x8*)&osm[wave][row][col];
    const int qg = blockIdx.y * 128 + wave * 32 + row;
    *(bf16x8*)(att + (size_t)(b * 2048 + qg) * 768 + h * 64 + col) = vv;
  }
}

// ------------------------------------------------------------------- gemm_o
// d_out[8192][1024] = attb[8192][768] x WoT[1024][768]^T + bo.
// Same structure + marching pointers; K=768 -> 24 steps.
__global__ __launch_bounds__(256)
void gemm_o(const u16* __restrict__ A, const u16* __restrict__ Bt,
            float* __restrict__ Cp, const float* __restrict__ bias)
{
  __shared__ __align__(16) u16 As[2][128 * 32];
  __shared__ __align__(16) u16 Bs[2][128 * 32];
  const int tid  = threadIdx.x;
  const int lane = tid & 63;
  const int wave = tid >> 6;
  const int bm = blockIdx.x * 128;
  const int bn = blockIdx.y * 128;
  const int wm = (wave >> 1) * 64;
  const int wn = (wave & 1) * 64;
  const int fr = lane & 15;
  const int fkb = (lane >> 4) * 16;

  f32x4 acc[4][4] = {};

  const char* pA0; const char* pA1; const char* pB0; const char* pB1;
  {
    const char* gA0 = (const char*)(A  + (size_t)bm * 768);
    const char* gB0 = (const char*)(Bt + (size_t)bn * 768);
    const int o0 = tid * 16, o1 = tid * 16 + 4096;
    const int r0 = o0 >> 6, r1 = o1 >> 6;
    const int s0 = (o0 & 63) ^ (((r0 >> 1) & 3) << 4);
    const int s1 = (o1 & 63) ^ (((r1 >> 1) & 3) << 4);
    pA0 = gA0 + (size_t)r0 * 1536 + s0;  pA1 = gA0 + (size_t)r1 * 1536 + s1;
    pB0 = gB0 + (size_t)r0 * 1536 + s0;  pB1 = gB0 + (size_t)r1 * 1536 + s1;
  }
  char* const dA0 = (char*)&As[0][0] + wave * 1024;
  char* const dB0 = (char*)&Bs[0][0] + wave * 1024;

  auto stage = [&](int buf) {
    char* da = dA0 + (buf << 13);
    char* db = dB0 + (buf << 13);
    gload16(pA0, da);        gload16(pB0, db);
    gload16(pA1, da + 4096); gload16(pB1, db + 4096);
    pA0 += 64; pA1 += 64; pB0 += 64; pB1 += 64;
  };

  int offA[4], offB[4];
#pragma unroll
  for (int m = 0; m < 4; ++m) {
    const int row = wm + m * 16 + fr;
    offA[m] = row * 64 + (fkb ^ (((row >> 1) & 3) << 4));
  }
#pragma unroll
  for (int n = 0; n < 4; ++n) {
    const int row = wn + n * 16 + fr;
    offB[n] = row * 64 + (fkb ^ (((row >> 1) & 3) << 4));
  }

  auto step = [&](int cur) {
    const char* ba = (const char*)&As[0][0] + (cur << 13);
    const char* bb = (const char*)&Bs[0][0] + (cur << 13);
    bf16x8 af[4], bg[4];
#pragma unroll
    for (int m = 0; m < 4; ++m) af[m] = *(const bf16x8*)(ba + offA[m]);
#pragma unroll
    for (int n = 0; n < 4; ++n) bg[n] = *(const bf16x8*)(bb + offB[n]);
#pragma unroll
    for (int m = 0; m < 4; ++m)
#pragma unroll
      for (int n = 0; n < 4; ++n)
        acc[m][n] = mfma16(af[m], bg[n], acc[m][n]);
  };

  stage(0);
#pragma unroll 1
  for (int t = 0; t < 23; ++t) {
    stage((t & 1) ^ 1);
    WAIT(4);
    BAR();
    step(t & 1);
    BAR();
    asm volatile("" ::: "memory");
  }
  WAIT(0);
  BAR();
  step(23 & 1);

  const int orow0 = bm + wm + 4 * (lane >> 4);
  const int ocol0 = bn + wn + fr;
#pragma unroll
  for (int m = 0; m < 4; ++m)
#pragma unroll
    for (int n = 0; n < 4; ++n)
#pragma unroll
      for (int r = 0; r < 4; ++r) {
        const int row = orow0 + m * 16 + r;
        const int col = ocol0 + n * 16;
        Cp[(size_t)row * 1024 + col] = acc[m][n][r] + bias[col];
      }
}

// ------------------------------------------------------------------ launch
extern "C" void kernel_launch(void* const* d_in, const int* in_sizes, int n_in,
                              void* d_out, int out_size, void* d_ws, size_t ws_size,
                              hipStream_t stream)
{
  const float* x     = (const float*)d_in[0];
  const float* tabx  = (const float*)d_in[1];
  const float* tab_g = (const float*)d_in[2];
  const float* tab_b = (const float*)d_in[3];
  const float* vid_g = (const float*)d_in[4];
  const float* vid_b = (const float*)d_in[5];
  const float* Wq    = (const float*)d_in[6];
  const float* Wk    = (const float*)d_in[7];
  const float* Wv    = (const float*)d_in[8];
  const float* q_g   = (const float*)d_in[9];
  const float* q_b   = (const float*)d_in[10];
  const float* k_g   = (const float*)d_in[11];
  const float* k_b   = (const float*)d_in[12];
  const float* Wo    = (const float*)d_in[13];
  const float* bo    = (const float*)d_in[14];

  char* ws = (char*)d_ws;
  const size_t O_WQT  = 0;
  const size_t O_WKVT = O_WQT  + (size_t)768 * 1024 * 2;   // 1536x1024 (Wk | Wv)
  const size_t O_WOT  = O_WKVT + (size_t)1536 * 1024 * 2;
  const size_t O_XN   = O_WOT  + (size_t)1024 * 768 * 2;
  const size_t O_KVN  = O_XN   + (size_t)8192 * 1024 * 2;
  const size_t O_QPRE = O_KVN  + (size_t)4096 * 1024 * 2;
  const size_t O_KPRE = O_QPRE + (size_t)8192 * 768 * 2;
  const size_t O_QB   = O_KPRE + (size_t)4096 * 768 * 2;
  const size_t O_KB   = O_QB   + (size_t)8192 * 768 * 2;
  const size_t O_VT   = O_KB   + (size_t)4096 * 768 * 2;
  const size_t O_ATT  = O_QPRE;   // alias: q_pre dead after its LN

  u16*   WqT   = (u16*)(ws + O_WQT);
  u16*   WkvT  = (u16*)(ws + O_WKVT);
  u16*   WoT   = (u16*)(ws + O_WOT);
  u16*   xn    = (u16*)(ws + O_XN);
  u16*   kvn   = (u16*)(ws + O_KVN);
  u16*   q_pre = (u16*)(ws + O_QPRE);
  u16*   k_pre = (u16*)(ws + O_KPRE);
  u16*   qb    = (u16*)(ws + O_QB);
  u16*   kb    = (u16*)(ws + O_KB);
  u16*   vT    = (u16*)(ws + O_VT);
  u16*   attb  = (u16*)(ws + O_ATT);

  prep<<<16128, 256, 0, stream>>>(Wq, Wk, Wv, Wo, WqT, WkvT, WoT,
                                  tabx, tab_g, tab_b, x, vid_g, vid_b, kvn, xn);
  gemm_qkv<<<768, 256, 0, stream>>>(xn, kvn, WqT, WkvT, q_pre, k_pre, vT);
  ln_qk<<<12288, 256, 0, stream>>>(k_pre, k_g, k_b, kb, q_pre, q_g, q_b, qb);
  attn7<<<dim3(48, 16), 256, 0, stream>>>(qb, kb, vT, attb);
  gemm_o<<<dim3(64, 8), 256, 0, stream>>>(attb, WoT, (float*)d_out, bo);
}